// Round 1
// baseline (3095.514 us; speedup 1.0000x reference)
//
#include <hip/hip_runtime.h>

typedef _Float16 f16;
typedef _Float16 f16x8 __attribute__((ext_vector_type(8)));
typedef float f32x4 __attribute__((ext_vector_type(4)));

#define DEV static __device__ __forceinline__

constexpr int  NPATCH = 1024;          // 4 * 16 * 16
constexpr int  LLEN   = 196;           // 14*14
constexpr long NLROWS = (long)NPATCH * LLEN;  // 200704

// async global->LDS, 16B per lane; dest = wave-uniform base + lane*16
DEV void g2l16(const void* g, void* l) {
  __builtin_amdgcn_global_load_lds(
      (const __attribute__((address_space(1))) unsigned int*)g,
      (__attribute__((address_space(3))) unsigned int*)l, 16, 0, 0);
}

// ---------------- k0: G = Wq^T Wk (f16), u = Wk^T bq (f32), Wv -> f16 ----------------
__global__ __launch_bounds__(256) void k0_prep(
    const float* __restrict__ Wq, const float* __restrict__ Wk,
    const float* __restrict__ Wv, const float* __restrict__ bq,
    f16* __restrict__ G16, f16* __restrict__ Wv16, float* __restrict__ u32) {
  int bx = blockIdx.x, t = threadIdx.x;
  if (bx < 256) {
    int c = bx;  // G row (uniform per block -> scalar loads of Wq)
    float acc = 0.f;
    for (int o = 0; o < 256; ++o) acc += Wq[o*256 + c] * Wk[o*256 + t];
    G16[c*256 + t] = (f16)acc;
  } else if (bx == 256) {
    float acc = 0.f;
    for (int o = 0; o < 256; ++o) acc += bq[o] * Wk[o*256 + t];
    u32[t] = acc;
  } else {
    for (int r = 0; r < 256; ++r) Wv16[r*256 + t] = (f16)Wv[r*256 + t];
  }
}

// ---------------- k1: resize(bilinear,half-pixel)+patchify+f16 pack -> dst[nm][256]; ub[nm]+=u.sp ----
__global__ __launch_bounds__(256) void k1_pack(
    const float* __restrict__ src, int Hs, int Ws, float invS,
    f16* __restrict__ dst, float* __restrict__ ub,
    const float* __restrict__ u32, int do_ub) {
  __shared__ float tile[224 * 65];   // [x][c-in-chunk], +1 pad breaks 64-way bank conflict
  __shared__ float us[64];
  int bx = blockIdx.x;
  int cc0 = (bx & 3) * 64;
  int bi = bx >> 2;
  int i  = bi % 14; bi /= 14;
  int py = bi & 15; int b = bi >> 4;
  int y = py*14 + i;
  float fy  = (y + 0.5f) * invS - 0.5f;
  float y0f = floorf(fy);
  float wy1 = fy - y0f, wy0 = 1.f - wy1;
  int y0 = (int)y0f, y1 = (int)y0f + 1;
  y0 = min(max(y0, 0), Hs-1); y1 = min(max(y1, 0), Hs-1);
  int t = threadIdx.x;
  if (t < 64) us[t] = u32[cc0 + t];
  int xl = t & 63, c4 = t >> 6;
  for (int xp = 0; xp < 4; ++xp) {
    int x = xp*64 + xl;
    if (x < 224) {
      float fx  = (x + 0.5f) * invS - 0.5f;
      float x0f = floorf(fx);
      float wx1 = fx - x0f, wx0 = 1.f - wx1;
      int x0 = (int)x0f, x1 = (int)x0f + 1;
      x0 = min(max(x0, 0), Ws-1); x1 = min(max(x1, 0), Ws-1);
      for (int co = 0; co < 16; ++co) {
        int c = cc0 + co*4 + c4;
        const float* base = src + ((long)(b*256 + c) * Hs) * Ws;
        float v;
        if (invS == 1.0f) {
          v = base[y0*Ws + x0];   // exact copy path for x
        } else {
          float v00 = base[y0*Ws + x0], v01 = base[y0*Ws + x1];
          float v10 = base[y1*Ws + x0], v11 = base[y1*Ws + x1];
          v = wy0*(wx0*v00 + wx1*v01) + wy1*(wx0*v10 + wx1*v11);
        }
        tile[x*65 + co*4 + c4] = v;
      }
    }
  }
  __syncthreads();
  int cp = t & 31, xg = t >> 5;            // 8 x-positions per pass, 32 c-pairs
  float u0 = us[2*cp], u1 = us[2*cp + 1];
  for (int xo = 0; xo < 28; ++xo) {
    int x = xo*8 + xg;
    float v0 = tile[x*65 + 2*cp], v1 = tile[x*65 + 2*cp + 1];
    int px = x / 14, j = x % 14;
    int m = i*14 + j;
    long nm = (long)(b*256 + py*16 + px) * 196 + m;
    union { f16 h[2]; unsigned uu; } pk;
    pk.h[0] = (f16)v0; pk.h[1] = (f16)v1;
    *(unsigned*)(dst + nm*256 + cc0 + 2*cp) = pk.uu;
    if (do_ub) {
      float part = u0*v0 + u1*v1;
      part += __shfl_xor(part, 1);
      part += __shfl_xor(part, 2);
      part += __shfl_xor(part, 4);
      part += __shfl_xor(part, 8);
      part += __shfl_xor(part, 16);
      if (cp == 0) atomicAdd(ub + nm, part);
    }
  }
}

// ---------------- k2: [Kt | V] = SPT * [G; Wv]^T. BM=64 nm-rows, BN=512, col-split waves ----------
// KtT[nm][256] (bt-layout for k3), V written transposed VT2[n][c][224] (bt-layout for k4)
__global__ __launch_bounds__(256) void k2_kv(
    const f16* __restrict__ SPT, const f16* __restrict__ G16,
    const f16* __restrict__ Wv16, f16* __restrict__ KtT, f16* __restrict__ VT2) {
  __shared__ __align__(16) char ldsA[64 * 80];    // [row][32 f16 -> 80B padded]
  __shared__ __align__(16) char ldsB[512 * 80];
  int tid = threadIdx.x;
  int lane = tid & 63, wv = tid >> 6;
  long nm0 = (long)blockIdx.x * 64;
  f32x4 zero = {0.f, 0.f, 0.f, 0.f};
  f32x4 acc[4][8];
#pragma unroll
  for (int a = 0; a < 4; ++a)
#pragma unroll
    for (int bb = 0; bb < 8; ++bb) acc[a][bb] = zero;
  int col0 = wv * 128;
  int r15 = lane & 15, quad = lane >> 4;
  for (int k0 = 0; k0 < 256; k0 += 32) {
    __syncthreads();
#pragma unroll
    for (int call = 0; call < 2; ++call) {       // A: 320 slots
      int slot = call*256 + tid;
      if (slot < 320) {
        int row = slot / 5, part = slot % 5;
        int pp_ = part < 4 ? part : 0;           // slot 5 = pad, dup row start
        g2l16(SPT + ((nm0 + row)*256 + k0 + pp_*8), ldsA + slot*16);
      }
    }
#pragma unroll
    for (int call = 0; call < 10; ++call) {      // B: 2560 slots
      int slot = call*256 + tid;
      int row = slot / 5, part = slot % 5;
      int pp_ = part < 4 ? part : 0;
      const f16* g = (row < 256) ? (G16 + (row*256 + k0 + pp_*8))
                                 : (Wv16 + ((row - 256)*256 + k0 + pp_*8));
      g2l16(g, ldsB + slot*16);
    }
    __syncthreads();
    f16x8 af[4];
#pragma unroll
    for (int rt = 0; rt < 4; ++rt)
      af[rt] = *(const f16x8*)(ldsA + (rt*16 + r15)*80 + quad*16);
#pragma unroll
    for (int tc = 0; tc < 8; ++tc) {
      f16x8 bf = *(const f16x8*)(ldsB + (col0 + tc*16 + r15)*80 + quad*16);
#pragma unroll
      for (int rt = 0; rt < 4; ++rt)
        acc[rt][tc] = __builtin_amdgcn_mfma_f32_16x16x32_f16(af[rt], bf, acc[rt][tc], 0, 0, 0);
    }
  }
#pragma unroll
  for (int rt = 0; rt < 4; ++rt)
#pragma unroll
    for (int tc = 0; tc < 8; ++tc) {
      int colc = col0 + tc*16 + r15;
#pragma unroll
      for (int reg = 0; reg < 4; ++reg) {
        long row = nm0 + rt*16 + quad*4 + reg;
        float v = acc[rt][tc][reg];
        if (colc < 256) {
          KtT[row*256 + colc] = (f16)v;
        } else {
          int o = colc - 256;
          int n = (int)(row / 196), m = (int)(row % 196);
          VT2[((long)(n*256 + o))*224 + m] = (f16)v;
        }
      }
    }
}

// ---------------- k3: S = XT . Kt^T per patch (+ub), row softmax -> P f16 [nl][224] ------------
__global__ __launch_bounds__(256) void k3_s(
    const f16* __restrict__ XT, const f16* __restrict__ KtT,
    const float* __restrict__ ub, f16* __restrict__ Pout) {
  __shared__ __align__(16) char ldsA[64 * 144];   // [l-row][64 f16 -> 144B padded]
  __shared__ __align__(16) char ldsB[208 * 144];  // [m-row][64 f16]
  __shared__ float ubs[208];
  int tid = threadIdx.x;
  int lane = tid & 63, wv = tid >> 6;
  int n  = blockIdx.x >> 2;
  int l0 = (blockIdx.x & 3) * 64;
  long base = (long)n * 196;
  for (int s = tid; s < 208; s += 256) ubs[s] = (s < 196) ? ub[base + s] : 0.f;
  f32x4 zero = {0.f, 0.f, 0.f, 0.f};
  f32x4 acc[13];
#pragma unroll
  for (int t = 0; t < 13; ++t) acc[t] = zero;
  int r15 = lane & 15, quad = lane >> 4;
  for (int k0 = 0; k0 < 256; k0 += 64) {
    __syncthreads();
#pragma unroll
    for (int call = 0; call < 3; ++call) {        // A: 576 slots (9 per row)
      int slot = call*256 + tid;
      if (slot < 576) {
        int row = slot / 9, part = slot % 9;
        int pp_ = part < 8 ? part : 0;
        int l = l0 + row; l = l > 195 ? 195 : l;  // clamp ghost rows
        g2l16(XT + ((base + l)*256 + k0 + pp_*8), ldsA + slot*16);
      }
    }
#pragma unroll
    for (int call = 0; call < 8; ++call) {        // B: 1872 slots
      int slot = call*256 + tid;
      if (slot < 1872) {
        int row = slot / 9, part = slot % 9;
        int pp_ = part < 8 ? part : 0;
        int m = row > 195 ? 195 : row;
        g2l16(KtT + ((base + m)*256 + k0 + pp_*8), ldsB + slot*16);
      }
    }
    __syncthreads();
#pragma unroll
    for (int ks = 0; ks < 2; ++ks) {
      f16x8 af = *(const f16x8*)(ldsA + (wv*16 + r15)*144 + (ks*4 + quad)*16);
#pragma unroll
      for (int t = 0; t < 13; ++t) {
        f16x8 bf = *(const f16x8*)(ldsB + (t*16 + r15)*144 + (ks*4 + quad)*16);
        acc[t] = __builtin_amdgcn_mfma_f32_16x16x32_f16(af, bf, acc[t], 0, 0, 0);
      }
    }
  }
  // softmax over m (cols). C-layout: col = lane&15 + 16*t, row = quad*4+reg (+16*wv +l0)
  float mx[4] = {-1e30f, -1e30f, -1e30f, -1e30f};
#pragma unroll
  for (int t = 0; t < 13; ++t) {
    int colb = t*16 + r15;
    float ubv = ubs[colb];
    bool valid = colb < 196;
#pragma unroll
    for (int reg = 0; reg < 4; ++reg) {
      float v = acc[t][reg] + ubv;
      acc[t][reg] = v;
      if (valid) mx[reg] = fmaxf(mx[reg], v);
    }
  }
#pragma unroll
  for (int reg = 0; reg < 4; ++reg) {
    float m = mx[reg];
    m = fmaxf(m, __shfl_xor(m, 1));
    m = fmaxf(m, __shfl_xor(m, 2));
    m = fmaxf(m, __shfl_xor(m, 4));
    m = fmaxf(m, __shfl_xor(m, 8));
    mx[reg] = m;
  }
  float sum[4] = {0.f, 0.f, 0.f, 0.f};
#pragma unroll
  for (int t = 0; t < 13; ++t) {
    int colb = t*16 + r15;
    bool valid = colb < 196;
#pragma unroll
    for (int reg = 0; reg < 4; ++reg) {
      float p = valid ? __expf(acc[t][reg] - mx[reg]) : 0.f;
      acc[t][reg] = p;
      sum[reg] += p;
    }
  }
#pragma unroll
  for (int reg = 0; reg < 4; ++reg) {
    float s = sum[reg];
    s += __shfl_xor(s, 1);
    s += __shfl_xor(s, 2);
    s += __shfl_xor(s, 4);
    s += __shfl_xor(s, 8);
    sum[reg] = 1.0f / s;
  }
#pragma unroll
  for (int reg = 0; reg < 4; ++reg) {
    int l = l0 + wv*16 + quad*4 + reg;
    if (l < 196) {
      long prow = (base + l) * 224;
#pragma unroll
      for (int t = 0; t < 13; ++t)
        Pout[prow + t*16 + r15] = (f16)(acc[t][reg] * sum[reg]);
      Pout[prow + 208 + r15] = (f16)0.f;    // zero pad m in [208,224)
    }
  }
}

// ---------------- k4: O = P . V^T, unpatchify epilogue into d_out ------------------------------
__global__ __launch_bounds__(256) void k4_o(
    const f16* __restrict__ Pbuf, const f16* __restrict__ VT2,
    const float* __restrict__ bv, float* __restrict__ out, int mode) {
  __shared__ __align__(16) char ldsA[64 * 80];    // P tile [l][32 f16]
  __shared__ __align__(16) char ldsB[256 * 80];   // V tile [c][32 f16]
  int tid = threadIdx.x;
  int lane = tid & 63, wv = tid >> 6;
  int n  = blockIdx.x >> 2;
  int l0 = (blockIdx.x & 3) * 64;
  int b = n >> 8, py = (n >> 4) & 15, px = n & 15;
  f32x4 zero = {0.f, 0.f, 0.f, 0.f};
  f32x4 acc[16];
#pragma unroll
  for (int t = 0; t < 16; ++t) acc[t] = zero;
  int r15 = lane & 15, quad = lane >> 4;
  for (int m0 = 0; m0 < 224; m0 += 32) {
    __syncthreads();
#pragma unroll
    for (int call = 0; call < 2; ++call) {        // A: 320 slots
      int slot = call*256 + tid;
      if (slot < 320) {
        int row = slot / 5, part = slot % 5;
        int pp_ = part < 4 ? part : 0;
        long nl = (long)n*196 + l0 + row;
        if (nl > NLROWS - 1) nl = NLROWS - 1;     // last-patch ghost rows
        g2l16(Pbuf + (nl*224 + m0 + pp_*8), ldsA + slot*16);
      }
    }
#pragma unroll
    for (int call = 0; call < 5; ++call) {        // B: 1280 slots
      int slot = call*256 + tid;
      int row = slot / 5, part = slot % 5;
      int pp_ = part < 4 ? part : 0;
      g2l16(VT2 + (((long)(n*256 + row))*224 + m0 + pp_*8), ldsB + slot*16);
    }
    __syncthreads();
    f16x8 af = *(const f16x8*)(ldsA + (wv*16 + r15)*80 + quad*16);
#pragma unroll
    for (int t = 0; t < 16; ++t) {
      f16x8 bf = *(const f16x8*)(ldsB + (t*16 + r15)*80 + quad*16);
      acc[t] = __builtin_amdgcn_mfma_f32_16x16x32_f16(af, bf, acc[t], 0, 0, 0);
    }
  }
#pragma unroll
  for (int reg = 0; reg < 4; ++reg) {
    int l = l0 + wv*16 + quad*4 + reg;
    if (l < 196) {
      int i = l / 14, j = l % 14;
      int yy = py*14 + i, xx = px*14 + j;
#pragma unroll
      for (int t = 0; t < 16; ++t) {
        int c = t*16 + r15;
        long oaddr = (((long)(b*256 + c))*224 + yy)*224 + xx;
        float v = acc[t][reg];
        if (mode == 0) v += 2.0f * bv[c];
        else           v += out[oaddr];
        out[oaddr] = v;
      }
    }
  }
}

extern "C" void kernel_launch(void* const* d_in, const int* in_sizes, int n_in,
                              void* d_out, int out_size, void* d_ws, size_t ws_size,
                              hipStream_t stream) {
  (void)in_sizes; (void)n_in; (void)out_size; (void)ws_size;
  const float* x     = (const float*)d_in[0];
  const float* skip0 = (const float*)d_in[1];
  const float* skip1 = (const float*)d_in[2];
  const float* Wq    = (const float*)d_in[3];
  const float* bq    = (const float*)d_in[4];
  const float* Wk    = (const float*)d_in[5];
  // d_in[6] = bk: algebraically drops out of softmax (row-constant)
  const float* Wv    = (const float*)d_in[7];
  const float* bv    = (const float*)d_in[8];
  float* out = (float*)d_out;

  char* ws = (char*)d_ws;
  size_t off = 0;
  auto alloc = [&](size_t bytes) {
    char* p = ws + off;
    off += (bytes + 255) & ~(size_t)255;
    return p;
  };
  f16*   XT   = (f16*)  alloc((size_t)NLROWS * 256 * 2);   // x packed, f16 [nl][c]
  f16*   SPT  = (f16*)  alloc((size_t)NLROWS * 256 * 2);   // skip packed; region reused as P
  f16*   KtT  = (f16*)  alloc((size_t)NLROWS * 256 * 2);   // Ktilde [nm][c]
  f16*   VT2  = (f16*)  alloc((size_t)NPATCH * 256 * 224 * 2); // V [n][c][m(224)]
  float* ub   = (float*)alloc((size_t)NLROWS * 4);
  f16*   G16  = (f16*)  alloc(256 * 256 * 2);
  f16*   Wv16 = (f16*)  alloc(256 * 256 * 2);
  float* u32  = (float*)alloc(256 * 4);
  f16*   P    = SPT;   // P[nl][224] (89.9 MB) fits in SPT region (102.8 MB); SPT dead by k3

  k0_prep<<<258, 256, 0, stream>>>(Wq, Wk, Wv, bq, G16, Wv16, u32);
  k1_pack<<<3584, 256, 0, stream>>>(x, 224, 224, 1.0f, XT, nullptr, u32, 0);

  const float* skips[2] = {skip0, skip1};
  int   hs[2]   = {112, 56};
  float invs[2] = {0.5f, 0.25f};
  for (int s = 0; s < 2; ++s) {
    hipMemsetAsync(ub, 0, (size_t)NLROWS * 4, stream);
    k1_pack<<<3584, 256, 0, stream>>>(skips[s], hs[s], hs[s], invs[s], SPT, ub, u32, 1);
    k2_kv<<<3136, 256, 0, stream>>>(SPT, G16, Wv16, KtT, VT2);
    k3_s <<<4096, 256, 0, stream>>>(XT, KtT, ub, P);
    k4_o <<<4096, 256, 0, stream>>>(P, VT2, bv, out, s);
  }
}

// Round 2
// 1878.128 us; speedup vs baseline: 1.6482x; 1.6482x over previous
//
#include <hip/hip_runtime.h>

typedef _Float16 f16;
typedef _Float16 f16x8 __attribute__((ext_vector_type(8)));
typedef float f32x4 __attribute__((ext_vector_type(4)));

#define DEV static __device__ __forceinline__

constexpr int  NPATCH = 1024;          // 4 * 16 * 16
constexpr int  LLEN   = 196;           // 14*14
constexpr long NLROWS = (long)NPATCH * LLEN;  // 200704

// async global->LDS, 16B per lane; dest = wave-uniform base + lane*16
DEV void g2l16(const void* g, void* l) {
  __builtin_amdgcn_global_load_lds(
      (const __attribute__((address_space(1))) unsigned int*)g,
      (__attribute__((address_space(3))) unsigned int*)l, 16, 0, 0);
}

// ---------------- k0: G = Wq^T Wk (f16), u = Wk^T bq (f32), Wv -> f16 ----------------
__global__ __launch_bounds__(256) void k0_prep(
    const float* __restrict__ Wq, const float* __restrict__ Wk,
    const float* __restrict__ Wv, const float* __restrict__ bq,
    f16* __restrict__ G16, f16* __restrict__ Wv16, float* __restrict__ u32) {
  int bx = blockIdx.x, t = threadIdx.x;
  if (bx < 256) {
    int c = bx;  // G row (uniform per block -> scalar loads of Wq)
    float acc = 0.f;
    for (int o = 0; o < 256; ++o) acc += Wq[o*256 + c] * Wk[o*256 + t];
    G16[c*256 + t] = (f16)acc;
  } else if (bx == 256) {
    float acc = 0.f;
    for (int o = 0; o < 256; ++o) acc += bq[o] * Wk[o*256 + t];
    u32[t] = acc;
  } else {
    for (int r = 0; r < 256; ++r) Wv16[r*256 + t] = (f16)Wv[r*256 + t];
  }
}

// ---------------- k1: resize(bilinear,half-pixel)+patchify+f16 pack -> dst[nm][256]; ub[nm]+=u.sp ----
__global__ __launch_bounds__(256) void k1_pack(
    const float* __restrict__ src, int Hs, int Ws, float invS,
    f16* __restrict__ dst, float* __restrict__ ub,
    const float* __restrict__ u32, int do_ub) {
  __shared__ float tile[224 * 65];   // [x][c-in-chunk], +1 pad breaks 64-way bank conflict
  __shared__ float us[64];
  int bx = blockIdx.x;
  int cc0 = (bx & 3) * 64;
  int bi = bx >> 2;
  int i  = bi % 14; bi /= 14;
  int py = bi & 15; int b = bi >> 4;
  int y = py*14 + i;
  float fy  = (y + 0.5f) * invS - 0.5f;
  float y0f = floorf(fy);
  float wy1 = fy - y0f, wy0 = 1.f - wy1;
  int y0 = (int)y0f, y1 = (int)y0f + 1;
  y0 = min(max(y0, 0), Hs-1); y1 = min(max(y1, 0), Hs-1);
  int t = threadIdx.x;
  if (t < 64) us[t] = u32[cc0 + t];
  int xl = t & 63, c4 = t >> 6;
  for (int xp = 0; xp < 4; ++xp) {
    int x = xp*64 + xl;
    if (x < 224) {
      float fx  = (x + 0.5f) * invS - 0.5f;
      float x0f = floorf(fx);
      float wx1 = fx - x0f, wx0 = 1.f - wx1;
      int x0 = (int)x0f, x1 = (int)x0f + 1;
      x0 = min(max(x0, 0), Ws-1); x1 = min(max(x1, 0), Ws-1);
      for (int co = 0; co < 16; ++co) {
        int c = cc0 + co*4 + c4;
        const float* base = src + ((long)(b*256 + c) * Hs) * Ws;
        float v;
        if (invS == 1.0f) {
          v = base[y0*Ws + x0];   // exact copy path for x
        } else {
          float v00 = base[y0*Ws + x0], v01 = base[y0*Ws + x1];
          float v10 = base[y1*Ws + x0], v11 = base[y1*Ws + x1];
          v = wy0*(wx0*v00 + wx1*v01) + wy1*(wx0*v10 + wx1*v11);
        }
        tile[x*65 + co*4 + c4] = v;
      }
    }
  }
  __syncthreads();
  int cp = t & 31, xg = t >> 5;            // 8 x-positions per pass, 32 c-pairs
  float u0 = us[2*cp], u1 = us[2*cp + 1];
  for (int xo = 0; xo < 28; ++xo) {
    int x = xo*8 + xg;
    float v0 = tile[x*65 + 2*cp], v1 = tile[x*65 + 2*cp + 1];
    int px = x / 14, j = x % 14;
    int m = i*14 + j;
    long nm = (long)(b*256 + py*16 + px) * 196 + m;
    union { f16 h[2]; unsigned uu; } pk;
    pk.h[0] = (f16)v0; pk.h[1] = (f16)v1;
    *(unsigned*)(dst + nm*256 + cc0 + 2*cp) = pk.uu;
    if (do_ub) {
      float part = u0*v0 + u1*v1;
      part += __shfl_xor(part, 1);
      part += __shfl_xor(part, 2);
      part += __shfl_xor(part, 4);
      part += __shfl_xor(part, 8);
      part += __shfl_xor(part, 16);
      if (cp == 0) atomicAdd(ub + nm, part);
    }
  }
}

// ---------------- k2: [Kt | V] = SPT * [G; Wv]^T. BM=64 nm-rows, BN=512, col-split waves ----------
// KtT[nm][256] (bt-layout for k3), V transposed via LDS -> VT2[n][c][224] (bt-layout for k4)
__global__ __launch_bounds__(256) void k2_kv(
    const f16* __restrict__ SPT, const f16* __restrict__ G16,
    const f16* __restrict__ Wv16, f16* __restrict__ KtT, f16* __restrict__ VT2) {
  __shared__ __align__(16) char ldsA[64 * 80];    // [row][32 f16 -> 80B padded]
  __shared__ __align__(16) char ldsB[512 * 80];   // reused as [64][258] f16 for V transpose
  int tid = threadIdx.x;
  int lane = tid & 63, wv = tid >> 6;
  long nm0 = (long)blockIdx.x * 64;
  f32x4 zero = {0.f, 0.f, 0.f, 0.f};
  f32x4 acc[4][8];
#pragma unroll
  for (int a = 0; a < 4; ++a)
#pragma unroll
    for (int bb = 0; bb < 8; ++bb) acc[a][bb] = zero;
  int col0 = wv * 128;
  int r15 = lane & 15, quad = lane >> 4;
  for (int k0 = 0; k0 < 256; k0 += 32) {
    __syncthreads();
#pragma unroll
    for (int call = 0; call < 2; ++call) {       // A: 320 slots
      int slot = call*256 + tid;
      if (slot < 320) {
        int row = slot / 5, part = slot % 5;
        int pp_ = part < 4 ? part : 0;           // slot 5 = pad, dup row start
        g2l16(SPT + ((nm0 + row)*256 + k0 + pp_*8), ldsA + slot*16);
      }
    }
#pragma unroll
    for (int call = 0; call < 10; ++call) {      // B: 2560 slots
      int slot = call*256 + tid;
      int row = slot / 5, part = slot % 5;
      int pp_ = part < 4 ? part : 0;
      const f16* g = (row < 256) ? (G16 + (row*256 + k0 + pp_*8))
                                 : (Wv16 + ((row - 256)*256 + k0 + pp_*8));
      g2l16(g, ldsB + slot*16);
    }
    __syncthreads();
    f16x8 af[4];
#pragma unroll
    for (int rt = 0; rt < 4; ++rt)
      af[rt] = *(const f16x8*)(ldsA + (rt*16 + r15)*80 + quad*16);
#pragma unroll
    for (int tc = 0; tc < 8; ++tc) {
      f16x8 bf = *(const f16x8*)(ldsB + (col0 + tc*16 + r15)*80 + quad*16);
#pragma unroll
      for (int rt = 0; rt < 4; ++rt)
        acc[rt][tc] = __builtin_amdgcn_mfma_f32_16x16x32_f16(af[rt], bf, acc[rt][tc], 0, 0, 0);
    }
  }
  __syncthreads();                // last MFMA ldsB reads done before reuse
  f16* ldsV = (f16*)ldsB;        // [64][258] (+2 pad -> bank-conflict-free transpose)
  if (wv >= 2) {                 // waves 2,3 hold V columns: stage to LDS
#pragma unroll
    for (int rt = 0; rt < 4; ++rt)
#pragma unroll
      for (int tc = 0; tc < 8; ++tc) {
        int o = col0 - 256 + tc*16 + r15;
#pragma unroll
        for (int reg = 0; reg < 4; ++reg) {
          int row = rt*16 + quad*4 + reg;
          ldsV[row*258 + o] = (f16)acc[rt][tc][reg];
        }
      }
  } else {                       // waves 0,1: K-tilde, already coalesced
#pragma unroll
    for (int rt = 0; rt < 4; ++rt)
#pragma unroll
      for (int tc = 0; tc < 8; ++tc) {
        int colc = col0 + tc*16 + r15;
#pragma unroll
        for (int reg = 0; reg < 4; ++reg) {
          long row = nm0 + rt*16 + quad*4 + reg;
          KtT[row*256 + colc] = (f16)acc[rt][tc][reg];
        }
      }
  }
  __syncthreads();
  {                              // transpose-write V: contiguous along m
    int row = tid & 63;
    long nm = nm0 + row;
    int n = (int)(nm / 196), m = (int)(nm % 196);
    long vbase = ((long)n * 256) * 224 + m;
    int o0 = (tid >> 6) * 64;
    for (int it = 0; it < 64; ++it) {
      int o = o0 + it;
      VT2[vbase + (long)o * 224] = ldsV[row*258 + o];
    }
  }
}

// ---------------- k3: S = XT . Kt^T per patch (+ub), row softmax -> P f16 [nl][224] ------------
__global__ __launch_bounds__(256) void k3_s(
    const f16* __restrict__ XT, const f16* __restrict__ KtT,
    const float* __restrict__ ub, f16* __restrict__ Pout) {
  __shared__ __align__(16) char ldsA[64 * 144];   // [l-row][64 f16 -> 144B padded]
  __shared__ __align__(16) char ldsB[208 * 144];  // [m-row][64 f16]
  __shared__ float ubs[208];
  int tid = threadIdx.x;
  int lane = tid & 63, wv = tid >> 6;
  int bx = blockIdx.x;
  // XCD swizzle: 4 blocks sharing KtT[n] slice land 8 apart -> same XCD, adjacent in time
  int n  = ((bx >> 5) << 3) | (bx & 7);
  int l0 = ((bx >> 3) & 3) * 64;
  long base = (long)n * 196;
  for (int s = tid; s < 208; s += 256) ubs[s] = (s < 196) ? ub[base + s] : 0.f;
  f32x4 zero = {0.f, 0.f, 0.f, 0.f};
  f32x4 acc[13];
#pragma unroll
  for (int t = 0; t < 13; ++t) acc[t] = zero;
  int r15 = lane & 15, quad = lane >> 4;
  for (int k0 = 0; k0 < 256; k0 += 64) {
    __syncthreads();
#pragma unroll
    for (int call = 0; call < 3; ++call) {        // A: 576 slots (9 per row)
      int slot = call*256 + tid;
      if (slot < 576) {
        int row = slot / 9, part = slot % 9;
        int pp_ = part < 8 ? part : 0;
        int l = l0 + row; l = l > 195 ? 195 : l;  // clamp ghost rows
        g2l16(XT + ((base + l)*256 + k0 + pp_*8), ldsA + slot*16);
      }
    }
#pragma unroll
    for (int call = 0; call < 8; ++call) {        // B: 1872 slots
      int slot = call*256 + tid;
      if (slot < 1872) {
        int row = slot / 9, part = slot % 9;
        int pp_ = part < 8 ? part : 0;
        int m = row > 195 ? 195 : row;
        g2l16(KtT + ((base + m)*256 + k0 + pp_*8), ldsB + slot*16);
      }
    }
    __syncthreads();
#pragma unroll
    for (int ks = 0; ks < 2; ++ks) {
      f16x8 af = *(const f16x8*)(ldsA + (wv*16 + r15)*144 + (ks*4 + quad)*16);
#pragma unroll
      for (int t = 0; t < 13; ++t) {
        f16x8 bf = *(const f16x8*)(ldsB + (t*16 + r15)*144 + (ks*4 + quad)*16);
        acc[t] = __builtin_amdgcn_mfma_f32_16x16x32_f16(af, bf, acc[t], 0, 0, 0);
      }
    }
  }
  // softmax over m (cols). C-layout: col = lane&15 + 16*t, row = quad*4+reg (+16*wv +l0)
  float mx[4] = {-1e30f, -1e30f, -1e30f, -1e30f};
#pragma unroll
  for (int t = 0; t < 13; ++t) {
    int colb = t*16 + r15;
    float ubv = ubs[colb];
    bool valid = colb < 196;
#pragma unroll
    for (int reg = 0; reg < 4; ++reg) {
      float v = acc[t][reg] + ubv;
      acc[t][reg] = v;
      if (valid) mx[reg] = fmaxf(mx[reg], v);
    }
  }
#pragma unroll
  for (int reg = 0; reg < 4; ++reg) {
    float m = mx[reg];
    m = fmaxf(m, __shfl_xor(m, 1));
    m = fmaxf(m, __shfl_xor(m, 2));
    m = fmaxf(m, __shfl_xor(m, 4));
    m = fmaxf(m, __shfl_xor(m, 8));
    mx[reg] = m;
  }
  float sum[4] = {0.f, 0.f, 0.f, 0.f};
#pragma unroll
  for (int t = 0; t < 13; ++t) {
    int colb = t*16 + r15;
    bool valid = colb < 196;
#pragma unroll
    for (int reg = 0; reg < 4; ++reg) {
      float p = valid ? __expf(acc[t][reg] - mx[reg]) : 0.f;
      acc[t][reg] = p;
      sum[reg] += p;
    }
  }
#pragma unroll
  for (int reg = 0; reg < 4; ++reg) {
    float s = sum[reg];
    s += __shfl_xor(s, 1);
    s += __shfl_xor(s, 2);
    s += __shfl_xor(s, 4);
    s += __shfl_xor(s, 8);
    sum[reg] = 1.0f / s;
  }
#pragma unroll
  for (int reg = 0; reg < 4; ++reg) {
    int l = l0 + wv*16 + quad*4 + reg;
    if (l < 196) {
      long prow = (base + l) * 224;
#pragma unroll
      for (int t = 0; t < 13; ++t)
        Pout[prow + t*16 + r15] = (f16)(acc[t][reg] * sum[reg]);
      Pout[prow + 208 + r15] = (f16)0.f;    // zero pad m in [208,224)
    }
  }
}

// ---------------- k4: O = P . V^T -> Obuf f16 [n][l][c] (coalesced; mode1 = +=) ---------------
__global__ __launch_bounds__(256) void k4_o(
    const f16* __restrict__ Pbuf, const f16* __restrict__ VT2,
    f16* __restrict__ Obuf, int mode) {
  __shared__ __align__(16) char ldsA[64 * 80];    // P tile [l][32 f16]
  __shared__ __align__(16) char ldsB[256 * 80];   // V tile [c][32 f16]
  int tid = threadIdx.x;
  int lane = tid & 63, wv = tid >> 6;
  int bx = blockIdx.x;
  int n  = ((bx >> 5) << 3) | (bx & 7);           // XCD swizzle (VT2[n] slice reuse)
  int l0 = ((bx >> 3) & 3) * 64;
  f32x4 zero = {0.f, 0.f, 0.f, 0.f};
  f32x4 acc[16];
#pragma unroll
  for (int t = 0; t < 16; ++t) acc[t] = zero;
  int r15 = lane & 15, quad = lane >> 4;
  for (int m0 = 0; m0 < 224; m0 += 32) {
    __syncthreads();
#pragma unroll
    for (int call = 0; call < 2; ++call) {        // A: 320 slots
      int slot = call*256 + tid;
      if (slot < 320) {
        int row = slot / 5, part = slot % 5;
        int pp_ = part < 4 ? part : 0;
        long nl = (long)n*196 + l0 + row;
        if (nl > NLROWS - 1) nl = NLROWS - 1;     // ghost rows (discarded later)
        g2l16(Pbuf + (nl*224 + m0 + pp_*8), ldsA + slot*16);
      }
    }
#pragma unroll
    for (int call = 0; call < 5; ++call) {        // B: 1280 slots
      int slot = call*256 + tid;
      int row = slot / 5, part = slot % 5;
      int pp_ = part < 4 ? part : 0;
      g2l16(VT2 + (((long)(n*256 + row))*224 + m0 + pp_*8), ldsB + slot*16);
    }
    __syncthreads();
    f16x8 af = *(const f16x8*)(ldsA + (wv*16 + r15)*80 + quad*16);
#pragma unroll
    for (int t = 0; t < 16; ++t) {
      f16x8 bf = *(const f16x8*)(ldsB + (t*16 + r15)*80 + quad*16);
      acc[t] = __builtin_amdgcn_mfma_f32_16x16x32_f16(af, bf, acc[t], 0, 0, 0);
    }
  }
#pragma unroll
  for (int reg = 0; reg < 4; ++reg) {
    int l = l0 + wv*16 + quad*4 + reg;
    if (l < 196) {
      long orow = ((long)n*196 + l) * 256;
#pragma unroll
      for (int t = 0; t < 16; ++t) {
        int c = t*16 + r15;
        float v = acc[t][reg];
        if (mode == 0) Obuf[orow + c] = (f16)v;
        else           Obuf[orow + c] = (f16)(v + (float)Obuf[orow + c]);
      }
    }
  }
}

// ---------------- k5: unpatchify Obuf[n][l][c] -> out[b][c][yy][xx] + 2*bv -------------------
__global__ __launch_bounds__(256) void k5_unpatch(
    const f16* __restrict__ Obuf, const float* __restrict__ bv,
    float* __restrict__ out) {
  __shared__ float lds[64 * 225];   // [c_local][xx], stride 225 -> conflict-free both sides
  int bx = blockIdx.x;
  int cc = (bx & 3) * 64;  bx >>= 2;
  int i  = bx % 14; bx /= 14;
  int py = bx & 15; int b = bx >> 4;
  int t = threadIdx.x;
  int cl = t & 63, pg = t >> 6;
  for (int it = 0; it < 56; ++it) {
    int pr = it*4 + pg;            // (px,j) pair index, 0..223
    int px = pr / 14, j = pr % 14;
    int n = b*256 + py*16 + px;
    float v = (float)Obuf[((long)n*196 + i*14 + j)*256 + cc + cl];
    lds[cl*225 + px*14 + j] = v;
  }
  __syncthreads();
  int yy = py*14 + i;
  for (int c = 0; c < 64; ++c) {
    float bb = 2.0f * bv[cc + c];
    if (t < 224)
      out[(((long)(b*256 + cc + c))*224 + yy)*224 + t] = lds[c*225 + t] + bb;
  }
}

extern "C" void kernel_launch(void* const* d_in, const int* in_sizes, int n_in,
                              void* d_out, int out_size, void* d_ws, size_t ws_size,
                              hipStream_t stream) {
  (void)in_sizes; (void)n_in; (void)out_size; (void)ws_size;
  const float* x     = (const float*)d_in[0];
  const float* skip0 = (const float*)d_in[1];
  const float* skip1 = (const float*)d_in[2];
  const float* Wq    = (const float*)d_in[3];
  const float* bq    = (const float*)d_in[4];
  const float* Wk    = (const float*)d_in[5];
  // d_in[6] = bk: algebraically drops out of softmax (row-constant)
  const float* Wv    = (const float*)d_in[7];
  const float* bv    = (const float*)d_in[8];
  float* out = (float*)d_out;

  char* ws = (char*)d_ws;
  size_t off = 0;
  auto alloc = [&](size_t bytes) {
    char* p = ws + off;
    off += (bytes + 255) & ~(size_t)255;
    return p;
  };
  f16*   XT   = (f16*)  alloc((size_t)NLROWS * 256 * 2);   // x packed, f16 [nl][c]
  f16*   SPT  = (f16*)  alloc((size_t)NLROWS * 256 * 2);   // skip packed; region reused as P
  f16*   KtT  = (f16*)  alloc((size_t)NLROWS * 256 * 2);   // Ktilde [nm][c]
  f16*   VT2  = (f16*)  alloc((size_t)NPATCH * 256 * 224 * 2); // V [n][c][m(224)]
  f16*   Obuf = (f16*)  alloc((size_t)NLROWS * 256 * 2);   // O accum f16 [n][l][c]
  float* ub   = (float*)alloc((size_t)NLROWS * 4);
  f16*   G16  = (f16*)  alloc(256 * 256 * 2);
  f16*   Wv16 = (f16*)  alloc(256 * 256 * 2);
  float* u32  = (float*)alloc(256 * 4);
  f16*   P    = SPT;   // P[nl][224] (89.9 MB) fits in SPT region (102.8 MB); SPT dead by k3

  k0_prep<<<258, 256, 0, stream>>>(Wq, Wk, Wv, bq, G16, Wv16, u32);
  k1_pack<<<3584, 256, 0, stream>>>(x, 224, 224, 1.0f, XT, nullptr, u32, 0);

  const float* skips[2] = {skip0, skip1};
  int   hs[2]   = {112, 56};
  float invs[2] = {0.5f, 0.25f};
  for (int s = 0; s < 2; ++s) {
    hipMemsetAsync(ub, 0, (size_t)NLROWS * 4, stream);
    k1_pack<<<3584, 256, 0, stream>>>(skips[s], hs[s], hs[s], invs[s], SPT, ub, u32, 1);
    k2_kv<<<3136, 256, 0, stream>>>(SPT, G16, Wv16, KtT, VT2);
    k3_s <<<4096, 256, 0, stream>>>(XT, KtT, ub, P);
    k4_o <<<4096, 256, 0, stream>>>(P, VT2, Obuf, s);
  }
  k5_unpatch<<<3584, 256, 0, stream>>>(Obuf, bv, out);
}